// Round 1
// baseline (393.867 us; speedup 1.0000x reference)
//
#include <hip/hip_runtime.h>

typedef unsigned short u16;
typedef __attribute__((ext_vector_type(8))) short short8x;
typedef __attribute__((ext_vector_type(4))) float f32x4;

#define B_ 2
#define L_ 2048
#define HID_ 2048
#define H_ 8
#define HD_ 256

__device__ __forceinline__ u16 f2bf(float f) {
  union { float f; unsigned u; } v; v.f = f;
  unsigned r = v.u + 0x7FFFu + ((v.u >> 16) & 1u);
  return (u16)(r >> 16);
}
__device__ __forceinline__ float bf2f(u16 u) {
  union { unsigned u; float f; } v; v.u = ((unsigned)u) << 16;
  return v.f;
}

// x fp32 -> bf16, same layout. grid = nelem/4/256
__global__ __launch_bounds__(256) void cvt_x_kernel(const float4* __restrict__ in,
                                                    u16* __restrict__ out) {
  int idx = blockIdx.x * 256 + threadIdx.x;
  float4 v = in[idx];
  u16* o = out + (size_t)idx * 4;
  o[0] = f2bf(v.x); o[1] = f2bf(v.y); o[2] = f2bf(v.z); o[3] = f2bf(v.w);
}

// W fp32 [K][N] -> Wt bf16 [N][K]. grid (N/32, K/32), block (32,8)
__global__ __launch_bounds__(256) void cvt_wt_kernel(const float* __restrict__ W,
                                                     u16* __restrict__ Wt, int K, int N) {
  __shared__ float tile[32][33];
  int n0 = blockIdx.x * 32, k0 = blockIdx.y * 32;
  int tx = threadIdx.x, ty = threadIdx.y;
#pragma unroll
  for (int i = 0; i < 32; i += 8)
    tile[ty + i][tx] = W[(size_t)(k0 + ty + i) * N + n0 + tx];
  __syncthreads();
#pragma unroll
  for (int i = 0; i < 32; i += 8)
    Wt[(size_t)(n0 + ty + i) * K + k0 + tx] = f2bf(tile[tx][ty + i]);
}

// RoPE + head-permute. in: bf16 [B*L][nh*256]; out: bf16 [(b*nh+h)*L + l][256]
// idx enumerates (row, h, d) with d in [0,128) fastest.
__global__ __launch_bounds__(256) void rope_kernel(const u16* __restrict__ in,
                                                   u16* __restrict__ out, int nh_shift) {
  int idx = blockIdx.x * 256 + threadIdx.x;
  int nh = 1 << nh_shift;
  int d = idx & 127;
  int t = idx >> 7;
  int h = t & (nh - 1);
  int row = t >> nh_shift;  // b*L + l
  int l = row & (L_ - 1);
  int b = row >> 11;
  size_t ibase = (size_t)row * (nh * 256) + h * 256 + d;
  float x1 = bf2f(in[ibase]);
  float x2 = bf2f(in[ibase + 128]);
  // inv_freq = theta^(-d/128), theta=10000 ; log2(10000)=13.2877123795
  float f = exp2f(-(float)d * (13.287712379549449f / 128.0f));
  float ang = (float)l * f;
  float s, c;
  sincosf(ang, &s, &c);
  size_t obase = ((size_t)(b * nh + h) * L_ + l) * 256 + d;
  out[obase] = f2bf(x1 * c - x2 * s);
  out[obase + 128] = f2bf(x2 * c + x1 * s);
}

// vproj bf16 [B*L][256] -> vt bf16 [(b*256+d)][L]
__global__ __launch_bounds__(256) void vt_kernel(const u16* __restrict__ vproj,
                                                 u16* __restrict__ vt) {
  int idx = blockIdx.x * 256 + threadIdx.x;  // = (b*256+d)*2048 + l
  int l = idx & 2047;
  int d = (idx >> 11) & 255;
  int b = idx >> 19;
  vt[idx] = vproj[((size_t)b * 2048 + l) * 256 + d];
}

// C[M][N] = A[M][K] @ Bt[N][K]^T, bf16 in, fp32 acc, bf16 or fp32 out.
// 128x128 tile, BK=32, 4 waves in 2x2, each wave 64x64 (4x4 fragments).
template <int F32OUT>
__global__ __launch_bounds__(256) void gemm_bt_kernel(const u16* __restrict__ A,
                                                      const u16* __restrict__ Bt,
                                                      void* __restrict__ Cv,
                                                      int M, int N, int K) {
  __shared__ u16 As[128 * 32];
  __shared__ u16 Bs[128 * 32];
  const int tid = threadIdx.x;
  const int lane = tid & 63;
  const int w = tid >> 6;
  const int wr = w >> 1, wc = w & 1;
  const int m0 = blockIdx.y * 128, n0 = blockIdx.x * 128;
  const int l15 = lane & 15, l4 = lane >> 4;
  f32x4 acc[4][4] = {};
  for (int kt = 0; kt < K; kt += 32) {
#pragma unroll
    for (int i = 0; i < 2; ++i) {
      int c = tid + i * 256;
      int row = c >> 2, cin = c & 3;  // 4x16B chunks per 32-elem row
      *(float4*)(&As[row * 32 + cin * 8]) =
          *(const float4*)(A + (size_t)(m0 + row) * K + kt + cin * 8);
      *(float4*)(&Bs[row * 32 + cin * 8]) =
          *(const float4*)(Bt + (size_t)(n0 + row) * K + kt + cin * 8);
    }
    __syncthreads();
    short8x a[4], b[4];
#pragma unroll
    for (int m = 0; m < 4; ++m)
      a[m] = *(const short8x*)(&As[(wr * 64 + m * 16 + l15) * 32 + l4 * 8]);
#pragma unroll
    for (int n = 0; n < 4; ++n)
      b[n] = *(const short8x*)(&Bs[(wc * 64 + n * 16 + l15) * 32 + l4 * 8]);
#pragma unroll
    for (int m = 0; m < 4; ++m)
#pragma unroll
      for (int n = 0; n < 4; ++n)
        acc[m][n] = __builtin_amdgcn_mfma_f32_16x16x32_bf16(a[m], b[n], acc[m][n], 0, 0, 0);
    __syncthreads();
  }
#pragma unroll
  for (int m = 0; m < 4; ++m) {
#pragma unroll
    for (int n = 0; n < 4; ++n) {
      int gcol = n0 + wc * 64 + n * 16 + l15;
#pragma unroll
      for (int r = 0; r < 4; ++r) {
        int grow = m0 + wr * 64 + m * 16 + l4 * 4 + r;
        if (F32OUT)
          ((float*)Cv)[(size_t)grow * N + gcol] = acc[m][n][r];
        else
          ((u16*)Cv)[(size_t)grow * N + gcol] = f2bf(acc[m][n][r]);
      }
    }
  }
}

// Flash attention. qb: [B*H][L][256], kb: [B][L][256], vt: [B][256][L],
// attn_o: [B*L][H*256]. Block = 128 threads (2 waves, 16 q-rows each, QBLK=32).
// grid.x = 32 pairs (block does q-tiles {pair, 63-pair} -> uniform causal work),
// grid.y = B*H.
__global__ __launch_bounds__(128) void flash_kernel(const u16* __restrict__ qb,
                                                    const u16* __restrict__ kb,
                                                    const u16* __restrict__ vt,
                                                    u16* __restrict__ attn_o) {
  __shared__ u16 Ks[32 * 264];    // [32][256] padded to 264
  __shared__ u16 Vts[256 * 40];   // [256][32] padded to 40
  __shared__ u16 Ps[2 * 16 * 72]; // per-wave [16][64] padded to 72
  const int pair = blockIdx.x;  // 0..31
  const int bh = blockIdx.y;    // 0..15
  const int b = bh >> 3;
  const int h = bh & 7;
  const int tid = threadIdx.x, lane = tid & 63, w = tid >> 6;
  const int l15 = lane & 15, l4 = lane >> 4;
  for (int qi = 0; qi < 2; ++qi) {
    const int qt = qi ? (63 - pair) : pair;
    const int q0 = qt * 32;
    const u16* qrow = qb + ((size_t)bh * L_ + q0 + w * 16 + l15) * 256;
    short8x qf[8];
#pragma unroll
    for (int kc = 0; kc < 8; ++kc)
      qf[kc] = *(const short8x*)(qrow + kc * 32 + l4 * 8);
    f32x4 o[16] = {};
    float mrow[4] = {-3e38f, -3e38f, -3e38f, -3e38f};
    float srow[4] = {0.f, 0.f, 0.f, 0.f};
    for (int t = 0; t <= qt; ++t) {
      // stage K tile [32][256] and V^T tile [256][32] (1024 16B-chunks each)
#pragma unroll
      for (int i = 0; i < 8; ++i) {
        int c = tid + i * 128;
        int rowk = c >> 5, cink = c & 31;
        *(float4*)(&Ks[rowk * 264 + cink * 8]) =
            *(const float4*)(kb + ((size_t)b * L_ + t * 32 + rowk) * 256 + cink * 8);
        int rowd = c >> 2, cind = c & 3;
        *(float4*)(&Vts[rowd * 40 + cind * 8]) =
            *(const float4*)(vt + ((size_t)b * 256 + rowd) * L_ + t * 32 + cind * 8);
      }
      __syncthreads();
      // S = Q K^T : 16 rows x 32 cols, contraction over d=256
      f32x4 sacc[2] = {};
#pragma unroll
      for (int n = 0; n < 2; ++n)
#pragma unroll
        for (int kc = 0; kc < 8; ++kc) {
          short8x kf = *(const short8x*)(&Ks[(n * 16 + l15) * 264 + kc * 32 + l4 * 8]);
          sacc[n] = __builtin_amdgcn_mfma_f32_16x16x32_bf16(qf[kc], kf, sacc[n], 0, 0, 0);
        }
      float p[2][4];
      const bool dm = (t == qt);
      const int ig = q0 + w * 16 + l4 * 4;
#pragma unroll
      for (int n = 0; n < 2; ++n) {
        int jg = t * 32 + n * 16 + l15;
#pragma unroll
        for (int r = 0; r < 4; ++r) {
          float v = sacc[n][r] * 0.0625f;  // HD^-0.5
          if (dm && (jg > ig + r)) v = -1e30f;
          p[n][r] = v;
        }
      }
      // online softmax per row (row lives in a 16-lane group)
#pragma unroll
      for (int r = 0; r < 4; ++r) {
        float rm = fmaxf(p[0][r], p[1][r]);
#pragma unroll
        for (int off = 1; off < 16; off <<= 1)
          rm = fmaxf(rm, __shfl_xor(rm, off));
        float mn = fmaxf(mrow[r], rm);
        float alpha = __expf(mrow[r] - mn);
        mrow[r] = mn;
        float e0 = __expf(p[0][r] - mn);
        float e1 = __expf(p[1][r] - mn);
        p[0][r] = e0; p[1][r] = e1;
        float rs = e0 + e1;
#pragma unroll
        for (int off = 1; off < 16; off <<= 1)
          rs += __shfl_xor(rs, off);
        srow[r] = srow[r] * alpha + rs;
#pragma unroll
        for (int ff = 0; ff < 16; ++ff) o[ff][r] *= alpha;
      }
      // P (C-layout) -> LDS -> A-layout fragment
#pragma unroll
      for (int n = 0; n < 2; ++n)
#pragma unroll
        for (int r = 0; r < 4; ++r)
          Ps[w * 1152 + (l4 * 4 + r) * 72 + n * 16 + l15] = f2bf(p[n][r]);
      asm volatile("s_waitcnt lgkmcnt(0)" ::: "memory");
      short8x paf = *(const short8x*)(&Ps[w * 1152 + l15 * 72 + l4 * 8]);
      // O += P V : contraction over j=32
#pragma unroll
      for (int ff = 0; ff < 16; ++ff) {
        short8x vf = *(const short8x*)(&Vts[(ff * 16 + l15) * 40 + l4 * 8]);
        o[ff] = __builtin_amdgcn_mfma_f32_16x16x32_bf16(paf, vf, o[ff], 0, 0, 0);
      }
      __syncthreads();
    }
#pragma unroll
    for (int r = 0; r < 4; ++r) {
      float inv = 1.0f / srow[r];
      int grow = q0 + w * 16 + l4 * 4 + r;
      size_t base = ((size_t)b * L_ + grow) * (size_t)(H_ * HD_) + h * 256;
#pragma unroll
      for (int ff = 0; ff < 16; ++ff)
        attn_o[base + ff * 16 + l15] = f2bf(o[ff][r] * inv);
    }
  }
}

extern "C" void kernel_launch(void* const* d_in, const int* in_sizes, int n_in,
                              void* d_out, int out_size, void* d_ws, size_t ws_size,
                              hipStream_t stream) {
  const float* x  = (const float*)d_in[0];
  const float* Wq = (const float*)d_in[1];
  const float* Wk = (const float*)d_in[2];
  const float* Wv = (const float*)d_in[3];
  const float* Wo = (const float*)d_in[4];
  // d_in[5] = additive causal mask: semantics reproduced analytically, not read.
  float* out = (float*)d_out;
  char* ws = (char*)d_ws;
  size_t off = 0;
  auto alloc = [&](size_t bytes) {
    void* p = ws + off;
    off = (off + bytes + 255) & ~(size_t)255;
    return p;
  };
  u16* wq_t  = (u16*)alloc(2048ull * 2048 * 2);  // [2048][2048] = Wq^T
  u16* wk_t  = (u16*)alloc(256ull * 2048 * 2);
  u16* wv_t  = (u16*)alloc(256ull * 2048 * 2);
  u16* wo_t  = (u16*)alloc(2048ull * 2048 * 2);
  u16* xbf   = (u16*)alloc(4096ull * 2048 * 2);  // reused as roped Q
  u16* qproj = (u16*)alloc(4096ull * 2048 * 2);  // reused as attn output
  u16* kproj = (u16*)alloc(4096ull * 256 * 2);
  u16* vproj = (u16*)alloc(4096ull * 256 * 2);
  u16* kb    = (u16*)alloc(4096ull * 256 * 2);
  u16* vtb   = (u16*)alloc(4096ull * 256 * 2);
  u16* qbuf   = xbf;    // alias: x_bf dead after V projection
  u16* attn_o = qproj;  // alias: qproj dead after rope_q

  cvt_x_kernel<<<8192, 256, 0, stream>>>((const float4*)x, xbf);
  cvt_wt_kernel<<<dim3(64, 64), dim3(32, 8), 0, stream>>>(Wq, wq_t, 2048, 2048);
  cvt_wt_kernel<<<dim3(8, 64),  dim3(32, 8), 0, stream>>>(Wk, wk_t, 2048, 256);
  cvt_wt_kernel<<<dim3(8, 64),  dim3(32, 8), 0, stream>>>(Wv, wv_t, 2048, 256);
  cvt_wt_kernel<<<dim3(64, 64), dim3(32, 8), 0, stream>>>(Wo, wo_t, 2048, 2048);

  gemm_bt_kernel<0><<<dim3(16, 32), 256, 0, stream>>>(xbf, wq_t, qproj, 4096, 2048, 2048);
  gemm_bt_kernel<0><<<dim3(2, 32),  256, 0, stream>>>(xbf, wk_t, kproj, 4096, 256, 2048);
  gemm_bt_kernel<0><<<dim3(2, 32),  256, 0, stream>>>(xbf, wv_t, vproj, 4096, 256, 2048);

  rope_kernel<<<16384, 256, 0, stream>>>(qproj, qbuf, 3);  // 8 heads
  rope_kernel<<<2048, 256, 0, stream>>>(kproj, kb, 0);     // 1 kv head
  vt_kernel<<<4096, 256, 0, stream>>>(vproj, vtb);

  flash_kernel<<<dim3(32, 16), 128, 0, stream>>>(qbuf, kb, vtb, attn_o);

  gemm_bt_kernel<1><<<dim3(16, 32), 256, 0, stream>>>(attn_o, wo_t, out, 4096, 2048, 2048);
}